// Round 3
// baseline (1249.548 us; speedup 1.0000x reference)
//
#include <hip/hip_runtime.h>
#include <math.h>

// Problem constants
// B=256, T=512, E=768, Hd=50, 4*Hd=200, H=100, K=11, START=9, STOP=10, NEG=-1000
// M = B*T = 131072

typedef _Float16 half8 __attribute__((ext_vector_type(8)));
typedef _Float16 half4 __attribute__((ext_vector_type(4)));
typedef float f32x4 __attribute__((ext_vector_type(4)));

// ---------------------------------------------------------------------------
// Kernel 1: xw[M][400] = emb[M][768] @ concat(W_ih_f, W_ih_b)^T
// Split-precision fp16 MFMA (hi+lo, 3 products) => ~fp32 accuracy at f16 rate.
// ---------------------------------------------------------------------------
__global__ __launch_bounds__(256) void k_gemm_split(
    const float* __restrict__ emb,
    const float* __restrict__ Wf,     // [200][768]
    const float* __restrict__ Wb,     // [200][768]
    float* __restrict__ xw)           // [M][400]
{
    __shared__ _Float16 Ah[128 * 64];
    __shared__ _Float16 Al[128 * 64];
    __shared__ _Float16 Bh[80 * 64];
    __shared__ _Float16 Bl[80 * 64];

    const int bid = blockIdx.x;
    const int wg  = (bid & 7) * 640 + (bid >> 3);
    const int mt  = wg / 5;
    const int nb  = wg - mt * 5;
    const size_t m0 = (size_t)mt * 128;
    const int n0 = nb * 80;

    const int tid  = threadIdx.x;
    const int lane = tid & 63;
    const int w    = tid >> 6;        // wave 0..3, rows w*32..+31
    const int grp  = lane >> 4;       // 0..3
    const int r16  = lane & 15;

    f32x4 acc[2][5];
    #pragma unroll
    for (int m = 0; m < 2; ++m)
        #pragma unroll
        for (int n = 0; n < 5; ++n) acc[m][n] = (f32x4){0.f, 0.f, 0.f, 0.f};

    for (int kt = 0; kt < 12; ++kt) {
        const int k0 = kt * 64;
        __syncthreads();

        #pragma unroll
        for (int j = 0; j < 8; ++j) {
            const int flat = j * 256 + tid;      // 0..2047 float4 slots
            const int row  = flat >> 4;          // 0..127
            const int q    = flat & 15;          // float4 col
            const float4 v = *(const float4*)(emb + (m0 + row) * 768 + k0 + q * 4);
            half4 hv, lv;
            hv[0] = (_Float16)v.x; lv[0] = (_Float16)(v.x - (float)hv[0]);
            hv[1] = (_Float16)v.y; lv[1] = (_Float16)(v.y - (float)hv[1]);
            hv[2] = (_Float16)v.z; lv[2] = (_Float16)(v.z - (float)hv[2]);
            hv[3] = (_Float16)v.w; lv[3] = (_Float16)(v.w - (float)hv[3]);
            const int s    = (q >> 1) ^ (row & 7);
            const int addr = row * 64 + s * 8 + (q & 1) * 4;
            *(half4*)(Ah + addr) = hv;
            *(half4*)(Al + addr) = lv;
        }
        #pragma unroll
        for (int j = 0; j < 5; ++j) {
            const int flat = j * 256 + tid;      // 0..1279
            const int row  = flat >> 4;          // 0..79
            const int q    = flat & 15;
            const int n    = n0 + row;
            const float* src = (n < 200) ? (Wf + (size_t)n * 768)
                                         : (Wb + (size_t)(n - 200) * 768);
            const float4 v = *(const float4*)(src + k0 + q * 4);
            half4 hv, lv;
            hv[0] = (_Float16)v.x; lv[0] = (_Float16)(v.x - (float)hv[0]);
            hv[1] = (_Float16)v.y; lv[1] = (_Float16)(v.y - (float)hv[1]);
            hv[2] = (_Float16)v.z; lv[2] = (_Float16)(v.z - (float)hv[2]);
            hv[3] = (_Float16)v.w; lv[3] = (_Float16)(v.w - (float)hv[3]);
            const int s    = (q >> 1) ^ (row & 7);
            const int addr = row * 64 + s * 8 + (q & 1) * 4;
            *(half4*)(Bh + addr) = hv;
            *(half4*)(Bl + addr) = lv;
        }
        __syncthreads();

        #pragma unroll
        for (int ks = 0; ks < 2; ++ks) {
            const int kslot = ks * 4 + grp;
            half8 ah[2], al[2], bh[5], bl[5];
            #pragma unroll
            for (int m = 0; m < 2; ++m) {
                const int row = w * 32 + m * 16 + r16;
                const int ad  = row * 64 + (kslot ^ (row & 7)) * 8;
                ah[m] = *(half8*)(Ah + ad);
                al[m] = *(half8*)(Al + ad);
            }
            #pragma unroll
            for (int n = 0; n < 5; ++n) {
                const int row = n * 16 + r16;
                const int ad  = row * 64 + (kslot ^ (row & 7)) * 8;
                bh[n] = *(half8*)(Bh + ad);
                bl[n] = *(half8*)(Bl + ad);
            }
            #pragma unroll
            for (int m = 0; m < 2; ++m)
                #pragma unroll
                for (int n = 0; n < 5; ++n) {
                    acc[m][n] = __builtin_amdgcn_mfma_f32_16x16x32_f16(ah[m], bh[n], acc[m][n], 0, 0, 0);
                    acc[m][n] = __builtin_amdgcn_mfma_f32_16x16x32_f16(ah[m], bl[n], acc[m][n], 0, 0, 0);
                    acc[m][n] = __builtin_amdgcn_mfma_f32_16x16x32_f16(al[m], bh[n], acc[m][n], 0, 0, 0);
                }
        }
    }

    #pragma unroll
    for (int m = 0; m < 2; ++m) {
        #pragma unroll
        for (int n = 0; n < 5; ++n) {
            #pragma unroll
            for (int i = 0; i < 4; ++i) {
                const size_t row = m0 + w * 32 + m * 16 + (lane >> 4) * 4 + i;
                const int    col = n0 + n * 16 + (lane & 15);
                xw[row * 400 + col] = acc[m][n][i];
            }
        }
    }
}

// ---------------------------------------------------------------------------
// Kernel 2: bidirectional LSTM recurrence. One block per (batch, dir).
// Wave w owns hidden units 16w..16w+15; lane = gate*16 + r16. Gate exchange
// is intra-wave (__shfl), c/h update parallel across waves, double-buffered
// h in LDS -> ONE barrier per step. 4-deep xw prefetch ring hides HBM/L3
// latency. Fast transcendentals (v_exp/v_rcp) shorten the serial path.
// ---------------------------------------------------------------------------
__global__ __launch_bounds__(256) void k_lstm(
    const float* __restrict__ xw,     // [131072][400] (fwd gates 0..199, bwd 200..399)
    const float* __restrict__ Whh_f,  // [200][50]
    const float* __restrict__ Whh_b,
    const float* __restrict__ bf_,    // [200]
    const float* __restrict__ bb_,
    float* __restrict__ hout)         // [131072][100] (fwd 0..49, bwd 50..99)
{
    const int b   = blockIdx.x >> 1;
    const int dir = blockIdx.x & 1;
    const int tid = threadIdx.x;
    const int wv  = tid >> 6;         // wave 0..3
    const int lane = tid & 63;
    const int g4  = lane >> 4;        // gate 0..3 (i,f,g,o)
    const int r16 = lane & 15;
    const int u   = wv * 16 + r16;    // hidden unit 0..63 (active < 50)
    const bool act = (u < 50);

    __shared__ __align__(16) float hb[2][52];

    const float* Whh  = dir ? Whh_b : Whh_f;
    const float* bias = dir ? bb_ : bf_;

    const int grow = g4 * 50 + u;     // gate row 0..199 (when act)
    float w[52];
    float bg = 0.f;
    if (act) {
        #pragma unroll
        for (int j = 0; j < 50; ++j) w[j] = Whh[grow * 50 + j];
        w[50] = 0.f; w[51] = 0.f;
        bg = bias[grow];
    } else {
        #pragma unroll
        for (int j = 0; j < 52; ++j) w[j] = 0.f;
    }

    if (tid < 104) ((float*)hb)[tid] = 0.f;
    float c = 0.f;
    __syncthreads();

    const size_t base = (size_t)b * 512;
    const int col = dir * 200 + grow;

    float xv[4];
    #pragma unroll
    for (int k = 0; k < 4; ++k) {
        const int tt = dir ? (511 - k) : k;
        xv[k] = act ? xw[(base + tt) * 400 + col] : 0.f;
    }

    int cur = 0;
    for (int it0 = 0; it0 < 512; it0 += 4) {
        #pragma unroll
        for (int k = 0; k < 4; ++k) {
            const int it = it0 + k;
            const int t  = dir ? (511 - it) : it;
            const float xcur = xv[k];
            if (it + 4 < 512) {
                const int tn = dir ? (511 - (it + 4)) : (it + 4);
                if (act) xv[k] = xw[(base + tn) * 400 + col];
            }

            const float4* h4 = (const float4*)(&hb[cur][0]);
            float s0 = bg + xcur, s1 = 0.f, s2 = 0.f, s3 = 0.f;
            #pragma unroll
            for (int q = 0; q < 13; ++q) {
                const float4 hv = h4[q];
                s0 = fmaf(w[4 * q + 0], hv.x, s0);
                s1 = fmaf(w[4 * q + 1], hv.y, s1);
                s2 = fmaf(w[4 * q + 2], hv.z, s2);
                s3 = fmaf(w[4 * q + 3], hv.w, s3);
            }
            const float sum = (s0 + s1) + (s2 + s3);

            const float gi = __shfl(sum, r16);
            const float gf = __shfl(sum, r16 + 16);
            const float gg = __shfl(sum, r16 + 32);
            const float go = __shfl(sum, r16 + 48);

            if (g4 == 0 && act) {
                const float si = __builtin_amdgcn_rcpf(1.f + __expf(-gi));
                const float sf = __builtin_amdgcn_rcpf(1.f + __expf(-gf));
                const float tg = 1.f - 2.f * __builtin_amdgcn_rcpf(__expf(2.f * gg) + 1.f);
                c = sf * c + si * tg;
                const float th = 1.f - 2.f * __builtin_amdgcn_rcpf(__expf(2.f * c) + 1.f);
                const float so = __builtin_amdgcn_rcpf(1.f + __expf(-go));
                const float h = so * th;
                hout[(base + t) * 100 + dir * 50 + u] = h;
                hb[cur ^ 1][u] = h;
            }
            __syncthreads();
            cur ^= 1;
        }
    }
}

// ---------------------------------------------------------------------------
// Kernel 3: emissions logits[bt][11] = hout[bt][100] @ Wout^T + bout
// ---------------------------------------------------------------------------
__global__ __launch_bounds__(256) void k_emis(
    const float* __restrict__ hout,   // [131072][100]
    const float* __restrict__ Wout,   // [11][100]
    const float* __restrict__ bout,   // [11]
    float* __restrict__ logits)       // [131072][11]
{
    __shared__ float Wl[1104];
    __shared__ float bl[11];
    const int tid = threadIdx.x;
    for (int i = tid; i < 1100; i += 256) Wl[i] = Wout[i];
    if (tid < 11) bl[tid] = bout[tid];
    __syncthreads();

    const size_t bt = (size_t)blockIdx.x * 256 + tid;
    const float4* h4 = (const float4*)(hout + bt * 100);
    float acc[11];
    #pragma unroll
    for (int k = 0; k < 11; ++k) acc[k] = bl[k];
    #pragma unroll
    for (int q = 0; q < 25; ++q) {
        float4 v = h4[q];
        #pragma unroll
        for (int k = 0; k < 11; ++k) {
            const float4 wv = *(const float4*)&Wl[k * 100 + q * 4];
            acc[k] = fmaf(v.x, wv.x, fmaf(v.y, wv.y, fmaf(v.z, wv.z, fmaf(v.w, wv.w, acc[k]))));
        }
    }
    #pragma unroll
    for (int k = 0; k < 11; ++k) logits[bt * 11 + k] = acc[k];
}

// ---------------------------------------------------------------------------
// Kernel 4: CRF forward scan + logsumexp score + fused Viterbi backtrace.
// ---------------------------------------------------------------------------
__global__ __launch_bounds__(64) void k_crf(
    const float* __restrict__ logits,   // [131072][11]
    const int* __restrict__ mask,       // [256][512]
    const float* __restrict__ trans,    // [11][11]
    float* __restrict__ scores,         // [256]
    float* __restrict__ paths)          // [256][512] (as float)
{
    const int b = blockIdx.x;
    const int lane = threadIdx.x;

    __shared__ float tr[121];
    __shared__ float al[12];
    __shared__ unsigned char bp[512][12];

    for (int i = lane; i < 121; i += 64) tr[i] = trans[i];
    if (lane < 12) al[lane] = (lane == 9) ? 0.f : -1000.f;
    __syncthreads();

    const size_t lbase = (size_t)b * 512;

    for (int t = 0; t < 512; ++t) {
        const int mt = mask[lbase + t];
        float na = 0.f; int amax = 0;
        if (lane < 11) {
            const float f = logits[(lbase + t) * 11 + lane];
            float vmax = -1e30f;
            float v[11];
            #pragma unroll
            for (int p = 0; p < 11; ++p) {
                float vv = (al[p] + f) + tr[p * 11 + lane];
                v[p] = vv;
                if (vv > vmax) { vmax = vv; amax = p; }
            }
            float s = 0.f;
            #pragma unroll
            for (int p = 0; p < 11; ++p) s += expf(v[p] - vmax);
            na = vmax + logf(s);
        }
        __syncthreads();
        if (lane < 11) {
            if (mt > 0) {
                al[lane] = na;
                bp[t][lane] = (unsigned char)amax;
            } else {
                bp[t][lane] = (unsigned char)lane;
            }
        }
        __syncthreads();
    }

    float fin = (lane < 11) ? (al[lane] + tr[lane * 11 + 10]) : -1e30f;
    float m = fin;
    int am = (lane < 11) ? lane : 1000;
    #pragma unroll
    for (int off = 8; off >= 1; off >>= 1) {
        float om = __shfl_xor(m, off, 16);
        int   oa = __shfl_xor(am, off, 16);
        if (om > m || (om == m && oa < am)) { m = om; am = oa; }
    }
    float s = (lane < 11) ? expf(fin - m) : 0.f;
    #pragma unroll
    for (int off = 8; off >= 1; off >>= 1) s += __shfl_xor(s, off, 16);

    if (lane == 0) {
        scores[b] = m + logf(s);
        int cur = am;
        paths[lbase + 511] = (float)cur;
        for (int t = 511; t >= 1; --t) {
            cur = bp[t][cur];
            paths[lbase + t - 1] = (float)cur;
        }
    }
}

// ---------------------------------------------------------------------------
extern "C" void kernel_launch(void* const* d_in, const int* in_sizes, int n_in,
                              void* d_out, int out_size, void* d_ws, size_t ws_size,
                              hipStream_t stream) {
    const float* emb   = (const float*)d_in[0];
    const int*   imask = (const int*)d_in[1];
    const float* Wihf  = (const float*)d_in[2];
    const float* Whhf  = (const float*)d_in[3];
    const float* bf_   = (const float*)d_in[4];
    const float* Wihb  = (const float*)d_in[5];
    const float* Whhb  = (const float*)d_in[6];
    const float* bb_   = (const float*)d_in[7];
    const float* Wout  = (const float*)d_in[8];
    const float* bout  = (const float*)d_in[9];
    const float* trans = (const float*)d_in[10];

    float* out = (float*)d_out;
    float* ws  = (float*)d_ws;
    float* xw     = ws;                          // 131072*400 f32 = 209.7 MB
    float* hout   = xw + (size_t)131072 * 400;   // 131072*100 f32 = 52.4 MB
    float* logits = hout + (size_t)131072 * 100; // 131072*11  f32 = 5.8 MB

    k_gemm_split<<<5120, 256, 0, stream>>>(emb, Wihf, Wihb, xw);
    k_lstm<<<512, 256, 0, stream>>>(xw, Whhf, Whhb, bf_, bb_, hout);
    k_emis<<<512, 256, 0, stream>>>(hout, Wout, bout, logits);
    k_crf<<<256, 64, 0, stream>>>(logits, imask, trans, out, out + 256);
}

// Round 4
// 1235.770 us; speedup vs baseline: 1.0111x; 1.0111x over previous
//
#include <hip/hip_runtime.h>
#include <math.h>

// Problem constants
// B=256, T=512, E=768, Hd=50, 4*Hd=200, H=100, K=11, START=9, STOP=10, NEG=-1000
// M = B*T = 131072

typedef _Float16 half8 __attribute__((ext_vector_type(8)));
typedef _Float16 half4 __attribute__((ext_vector_type(4)));
typedef float f32x4 __attribute__((ext_vector_type(4)));

// ---------------------------------------------------------------------------
// Kernel 1: xw[M][400] = emb[M][768] @ concat(W_ih_f, W_ih_b)^T
// Split-precision fp16 MFMA (hi+lo, 3 products) => ~fp32 accuracy at f16 rate.
// ---------------------------------------------------------------------------
__global__ __launch_bounds__(256) void k_gemm_split(
    const float* __restrict__ emb,
    const float* __restrict__ Wf,     // [200][768]
    const float* __restrict__ Wb,     // [200][768]
    float* __restrict__ xw)           // [M][400]
{
    __shared__ _Float16 Ah[128 * 64];
    __shared__ _Float16 Al[128 * 64];
    __shared__ _Float16 Bh[80 * 64];
    __shared__ _Float16 Bl[80 * 64];

    const int bid = blockIdx.x;
    const int wg  = (bid & 7) * 640 + (bid >> 3);
    const int mt  = wg / 5;
    const int nb  = wg - mt * 5;
    const size_t m0 = (size_t)mt * 128;
    const int n0 = nb * 80;

    const int tid  = threadIdx.x;
    const int lane = tid & 63;
    const int w    = tid >> 6;        // wave 0..3, rows w*32..+31
    const int grp  = lane >> 4;       // 0..3
    const int r16  = lane & 15;

    f32x4 acc[2][5];
    #pragma unroll
    for (int m = 0; m < 2; ++m)
        #pragma unroll
        for (int n = 0; n < 5; ++n) acc[m][n] = (f32x4){0.f, 0.f, 0.f, 0.f};

    for (int kt = 0; kt < 12; ++kt) {
        const int k0 = kt * 64;
        __syncthreads();

        #pragma unroll
        for (int j = 0; j < 8; ++j) {
            const int flat = j * 256 + tid;      // 0..2047 float4 slots
            const int row  = flat >> 4;          // 0..127
            const int q    = flat & 15;          // float4 col
            const float4 v = *(const float4*)(emb + (m0 + row) * 768 + k0 + q * 4);
            half4 hv, lv;
            hv[0] = (_Float16)v.x; lv[0] = (_Float16)(v.x - (float)hv[0]);
            hv[1] = (_Float16)v.y; lv[1] = (_Float16)(v.y - (float)hv[1]);
            hv[2] = (_Float16)v.z; lv[2] = (_Float16)(v.z - (float)hv[2]);
            hv[3] = (_Float16)v.w; lv[3] = (_Float16)(v.w - (float)hv[3]);
            const int s    = (q >> 1) ^ (row & 7);
            const int addr = row * 64 + s * 8 + (q & 1) * 4;
            *(half4*)(Ah + addr) = hv;
            *(half4*)(Al + addr) = lv;
        }
        #pragma unroll
        for (int j = 0; j < 5; ++j) {
            const int flat = j * 256 + tid;      // 0..1279
            const int row  = flat >> 4;          // 0..79
            const int q    = flat & 15;
            const int n    = n0 + row;
            const float* src = (n < 200) ? (Wf + (size_t)n * 768)
                                         : (Wb + (size_t)(n - 200) * 768);
            const float4 v = *(const float4*)(src + k0 + q * 4);
            half4 hv, lv;
            hv[0] = (_Float16)v.x; lv[0] = (_Float16)(v.x - (float)hv[0]);
            hv[1] = (_Float16)v.y; lv[1] = (_Float16)(v.y - (float)hv[1]);
            hv[2] = (_Float16)v.z; lv[2] = (_Float16)(v.z - (float)hv[2]);
            hv[3] = (_Float16)v.w; lv[3] = (_Float16)(v.w - (float)hv[3]);
            const int s    = (q >> 1) ^ (row & 7);
            const int addr = row * 64 + s * 8 + (q & 1) * 4;
            *(half4*)(Bh + addr) = hv;
            *(half4*)(Bl + addr) = lv;
        }
        __syncthreads();

        #pragma unroll
        for (int ks = 0; ks < 2; ++ks) {
            const int kslot = ks * 4 + grp;
            half8 ah[2], al[2], bh[5], bl[5];
            #pragma unroll
            for (int m = 0; m < 2; ++m) {
                const int row = w * 32 + m * 16 + r16;
                const int ad  = row * 64 + (kslot ^ (row & 7)) * 8;
                ah[m] = *(half8*)(Ah + ad);
                al[m] = *(half8*)(Al + ad);
            }
            #pragma unroll
            for (int n = 0; n < 5; ++n) {
                const int row = n * 16 + r16;
                const int ad  = row * 64 + (kslot ^ (row & 7)) * 8;
                bh[n] = *(half8*)(Bh + ad);
                bl[n] = *(half8*)(Bl + ad);
            }
            #pragma unroll
            for (int m = 0; m < 2; ++m)
                #pragma unroll
                for (int n = 0; n < 5; ++n) {
                    acc[m][n] = __builtin_amdgcn_mfma_f32_16x16x32_f16(ah[m], bh[n], acc[m][n], 0, 0, 0);
                    acc[m][n] = __builtin_amdgcn_mfma_f32_16x16x32_f16(ah[m], bl[n], acc[m][n], 0, 0, 0);
                    acc[m][n] = __builtin_amdgcn_mfma_f32_16x16x32_f16(al[m], bh[n], acc[m][n], 0, 0, 0);
                }
        }
    }

    #pragma unroll
    for (int m = 0; m < 2; ++m) {
        #pragma unroll
        for (int n = 0; n < 5; ++n) {
            #pragma unroll
            for (int i = 0; i < 4; ++i) {
                const size_t row = m0 + w * 32 + m * 16 + (lane >> 4) * 4 + i;
                const int    col = n0 + n * 16 + (lane & 15);
                xw[row * 400 + col] = acc[m][n][i];
            }
        }
    }
}

// ---------------------------------------------------------------------------
// Kernel 2: bidirectional LSTM recurrence. One block per (batch, dir).
// Wave w owns hidden units 16w..16w+15; lane = gate*16 + r16; gate exchange
// intra-wave via __shfl; double-buffered h in LDS; ONE raw s_barrier per
// step with lgkmcnt-only wait — global stores (hout) and the 4-deep xw
// prefetch ring stay in flight across steps (no vmcnt drain!).
// ---------------------------------------------------------------------------
__global__ __launch_bounds__(256) void k_lstm(
    const float* __restrict__ xw,     // [131072][400] (fwd gates 0..199, bwd 200..399)
    const float* __restrict__ Whh_f,  // [200][50]
    const float* __restrict__ Whh_b,
    const float* __restrict__ bf_,    // [200]
    const float* __restrict__ bb_,
    float* __restrict__ hout)         // [131072][100] (fwd 0..49, bwd 50..99)
{
    const int b   = blockIdx.x >> 1;
    const int dir = blockIdx.x & 1;
    const int tid = threadIdx.x;
    const int wv  = tid >> 6;         // wave 0..3
    const int lane = tid & 63;
    const int g4  = lane >> 4;        // gate 0..3 (i,f,g,o)
    const int r16 = lane & 15;
    const int u   = wv * 16 + r16;    // hidden unit 0..63 (active < 50)
    const bool act = (u < 50);

    __shared__ __align__(16) float hb[2][52];

    const float* Whh  = dir ? Whh_b : Whh_f;
    const float* bias = dir ? bb_ : bf_;

    const int grow = g4 * 50 + u;     // gate row 0..199 (when act)
    float w[52];
    float bg = 0.f;
    if (act) {
        #pragma unroll
        for (int j = 0; j < 50; ++j) w[j] = Whh[grow * 50 + j];
        w[50] = 0.f; w[51] = 0.f;
        bg = bias[grow];
    } else {
        #pragma unroll
        for (int j = 0; j < 52; ++j) w[j] = 0.f;
    }

    if (tid < 104) ((float*)hb)[tid] = 0.f;
    float c = 0.f;
    __syncthreads();

    const size_t base = (size_t)b * 512;
    const int col = dir * 200 + grow;

    float xv[4];
    #pragma unroll
    for (int k = 0; k < 4; ++k) {
        const int tt = dir ? (511 - k) : k;
        xv[k] = act ? xw[(base + tt) * 400 + col] : 0.f;
    }

    int cur = 0;
    for (int it0 = 0; it0 < 512; it0 += 4) {
        #pragma unroll
        for (int k = 0; k < 4; ++k) {
            const int it = it0 + k;
            const int t  = dir ? (511 - it) : it;
            const float xcur = xv[k];
            if (it + 4 < 512) {
                const int tn = dir ? (511 - (it + 4)) : (it + 4);
                if (act) xv[k] = xw[(base + tn) * 400 + col];
            }

            const float4* h4 = (const float4*)(&hb[cur][0]);
            float s0 = bg + xcur, s1 = 0.f, s2 = 0.f, s3 = 0.f;
            #pragma unroll
            for (int q = 0; q < 13; ++q) {
                const float4 hv = h4[q];
                s0 = fmaf(w[4 * q + 0], hv.x, s0);
                s1 = fmaf(w[4 * q + 1], hv.y, s1);
                s2 = fmaf(w[4 * q + 2], hv.z, s2);
                s3 = fmaf(w[4 * q + 3], hv.w, s3);
            }
            const float sum = (s0 + s1) + (s2 + s3);

            const float gi = __shfl(sum, r16);
            const float gf = __shfl(sum, r16 + 16);
            const float gg = __shfl(sum, r16 + 32);
            const float go = __shfl(sum, r16 + 48);

            if (g4 == 0 && act) {
                const float si = __builtin_amdgcn_rcpf(1.f + __expf(-gi));
                const float sf = __builtin_amdgcn_rcpf(1.f + __expf(-gf));
                const float tg = 1.f - 2.f * __builtin_amdgcn_rcpf(__expf(2.f * gg) + 1.f);
                c = sf * c + si * tg;
                const float th = 1.f - 2.f * __builtin_amdgcn_rcpf(__expf(2.f * c) + 1.f);
                const float so = __builtin_amdgcn_rcpf(1.f + __expf(-go));
                const float h = so * th;
                hout[(base + t) * 100 + dir * 50 + u] = h;
                hb[cur ^ 1][u] = h;
            }
            // LDS-visibility-only barrier: do NOT drain vmcnt (keeps hout
            // stores and the xw prefetch ring in flight across steps).
            asm volatile("s_waitcnt lgkmcnt(0)\n\ts_barrier" ::: "memory");
            cur ^= 1;
        }
    }
}

// ---------------------------------------------------------------------------
// Kernel 3: emissions logits[bt][11] = hout[bt][100] @ Wout^T + bout
// ---------------------------------------------------------------------------
__global__ __launch_bounds__(256) void k_emis(
    const float* __restrict__ hout,   // [131072][100]
    const float* __restrict__ Wout,   // [11][100]
    const float* __restrict__ bout,   // [11]
    float* __restrict__ logits)       // [131072][11]
{
    __shared__ float Wl[1104];
    __shared__ float bl[11];
    const int tid = threadIdx.x;
    for (int i = tid; i < 1100; i += 256) Wl[i] = Wout[i];
    if (tid < 11) bl[tid] = bout[tid];
    __syncthreads();

    const size_t bt = (size_t)blockIdx.x * 256 + tid;
    const float4* h4 = (const float4*)(hout + bt * 100);
    float acc[11];
    #pragma unroll
    for (int k = 0; k < 11; ++k) acc[k] = bl[k];
    #pragma unroll
    for (int q = 0; q < 25; ++q) {
        float4 v = h4[q];
        #pragma unroll
        for (int k = 0; k < 11; ++k) {
            const float4 wv = *(const float4*)&Wl[k * 100 + q * 4];
            acc[k] = fmaf(v.x, wv.x, fmaf(v.y, wv.y, fmaf(v.z, wv.z, fmaf(v.w, wv.w, acc[k]))));
        }
    }
    #pragma unroll
    for (int k = 0; k < 11; ++k) logits[bt * 11 + k] = acc[k];
}

// ---------------------------------------------------------------------------
// Kernel 4: CRF forward scan + logsumexp score + fused Viterbi backtrace.
// ONE wave per batch element -> NO barriers at all (lockstep wave64; LDS
// deps ordered by lgkmcnt). Transition column hoisted to registers; logits
// and mask double-buffered one step ahead. Arithmetic identical to the
// passing version (same op order, libm expf/logf).
// ---------------------------------------------------------------------------
__global__ __launch_bounds__(64) void k_crf(
    const float* __restrict__ logits,   // [131072][11]
    const int* __restrict__ mask,       // [256][512]
    const float* __restrict__ trans,    // [11][11]
    float* __restrict__ scores,         // [256]
    float* __restrict__ paths)          // [256][512] (as float)
{
    const int b = blockIdx.x;
    const int lane = threadIdx.x;

    __shared__ float al[12];
    __shared__ unsigned char bp[512][12];

    float trc[11];
    if (lane < 11) {
        #pragma unroll
        for (int p = 0; p < 11; ++p) trc[p] = trans[p * 11 + lane];
    } else {
        #pragma unroll
        for (int p = 0; p < 11; ++p) trc[p] = 0.f;
    }
    if (lane < 12) al[lane] = (lane == 9) ? 0.f : -1000.f;

    const size_t lbase = (size_t)b * 512;

    float f_cur = (lane < 11) ? logits[lbase * 11 + lane] : 0.f;
    int   m_cur = mask[lbase];

    for (int t = 0; t < 512; ++t) {
        float f_next = 0.f; int m_next = 1;
        if (t + 1 < 512) {
            if (lane < 11) f_next = logits[(lbase + t + 1) * 11 + lane];
            m_next = mask[lbase + t + 1];
        }

        if (lane < 11) {
            float vmax = -1e30f; int amax = 0;
            float v[11];
            #pragma unroll
            for (int p = 0; p < 11; ++p) {
                float vv = (al[p] + f_cur) + trc[p];
                v[p] = vv;
                if (vv > vmax) { vmax = vv; amax = p; }
            }
            float s = 0.f;
            #pragma unroll
            for (int p = 0; p < 11; ++p) s += expf(v[p] - vmax);
            const float na = vmax + logf(s);

            if (m_cur > 0) {
                al[lane] = na;
                bp[t][lane] = (unsigned char)amax;
            } else {
                bp[t][lane] = (unsigned char)lane;
            }
        }
        f_cur = f_next;
        m_cur = m_next;
    }

    // final scores + argmax (STOP = 10)
    float fin = (lane < 11) ? (al[lane] + trans[lane * 11 + 10]) : -1e30f;
    float m = fin;
    int am = (lane < 11) ? lane : 1000;
    #pragma unroll
    for (int off = 8; off >= 1; off >>= 1) {
        float om = __shfl_xor(m, off, 16);
        int   oa = __shfl_xor(am, off, 16);
        if (om > m || (om == m && oa < am)) { m = om; am = oa; }
    }
    float s = (lane < 11) ? expf(fin - m) : 0.f;
    #pragma unroll
    for (int off = 8; off >= 1; off >>= 1) s += __shfl_xor(s, off, 16);

    if (lane == 0) {
        scores[b] = m + logf(s);
        int cur = am;
        paths[lbase + 511] = (float)cur;
        for (int t = 511; t >= 1; --t) {
            cur = bp[t][cur];
            paths[lbase + t - 1] = (float)cur;
        }
    }
}

// ---------------------------------------------------------------------------
extern "C" void kernel_launch(void* const* d_in, const int* in_sizes, int n_in,
                              void* d_out, int out_size, void* d_ws, size_t ws_size,
                              hipStream_t stream) {
    const float* emb   = (const float*)d_in[0];
    const int*   imask = (const int*)d_in[1];
    const float* Wihf  = (const float*)d_in[2];
    const float* Whhf  = (const float*)d_in[3];
    const float* bf_   = (const float*)d_in[4];
    const float* Wihb  = (const float*)d_in[5];
    const float* Whhb  = (const float*)d_in[6];
    const float* bb_   = (const float*)d_in[7];
    const float* Wout  = (const float*)d_in[8];
    const float* bout  = (const float*)d_in[9];
    const float* trans = (const float*)d_in[10];

    float* out = (float*)d_out;
    float* ws  = (float*)d_ws;
    float* xw     = ws;                          // 131072*400 f32 = 209.7 MB
    float* hout   = xw + (size_t)131072 * 400;   // 131072*100 f32 = 52.4 MB
    float* logits = hout + (size_t)131072 * 100; // 131072*11  f32 = 5.8 MB

    k_gemm_split<<<5120, 256, 0, stream>>>(emb, Wihf, Wihb, xw);
    k_lstm<<<512, 256, 0, stream>>>(xw, Whhf, Whhb, bf_, bb_, hout);
    k_emis<<<512, 256, 0, stream>>>(hout, Wout, bout, logits);
    k_crf<<<256, 64, 0, stream>>>(logits, imask, trans, out, out + 256);
}